// Round 1
// baseline (1307.821 us; speedup 1.0000x reference)
//
#include <hip/hip_runtime.h>
#include <hip/hip_bf16.h>

#define HIDDEN 768
#define NB 8
#define BLK 96
#define S_LEN 8192
#define H_LEN 4096
#define M_LEN 4097
#define MP 4104          // padded row pitch (divisible by 8)
#define BATCH 4

#define TWO_PI 6.28318530717958647692f
#define INV_SQRT_N 0.011048543456039806f   // 1/sqrt(8192)
#define C_INV 0.022097086912079612f        // 2/sqrt(8192) = sqrt(N)/H
#define LAM 0.01f

__device__ __forceinline__ int rev12(int k) {
    return (int)(__brev((unsigned)k) >> 20);
}

// ---------------------------------------------------------------------------
// K1: forward rfft per (b,c).  x[b, :, c] (stride HIDDEN) -> Xr/Xi rows (bf16)
// Real FFT of length 8192 via 4096-pt complex in-place DIT FFT in LDS.
// ---------------------------------------------------------------------------
__global__ __launch_bounds__(256) void fft_fwd(const float* __restrict__ x,
                                               __hip_bfloat16* __restrict__ Xr,
                                               __hip_bfloat16* __restrict__ Xi) {
    __shared__ float sr[H_LEN];
    __shared__ float si[H_LEN];
    const int wg = blockIdx.x;           // 0 .. BATCH*HIDDEN-1
    const int b = wg / HIDDEN;
    const int c = wg % HIDDEN;
    const int tid = threadIdx.x;
    const float* xb = x + (size_t)b * S_LEN * HIDDEN + c;

    // load z[k] = x[2k] + i x[2k+1] into bit-reversed LDS slots
    for (int k = tid; k < H_LEN; k += 256) {
        float re = xb[(size_t)(2 * k) * HIDDEN];
        float im = xb[(size_t)(2 * k + 1) * HIDDEN];
        int r = rev12(k);
        sr[r] = re;
        si[r] = im;
    }
    __syncthreads();

    // 12 radix-2 DIT stages, forward (e^{-i})
    for (int len = 2; len <= H_LEN; len <<= 1) {
        const int half = len >> 1;
        const float inv_len = 1.0f / (float)len;
        for (int i = tid; i < H_LEN / 2; i += 256) {
            int j = i & (half - 1);
            int i1 = ((i - j) << 1) + j;
            int i2 = i1 + half;
            float ang = -TWO_PI * (float)j * inv_len;
            float wsn, wcs;
            __sincosf(ang, &wsn, &wcs);
            float ur = sr[i1], ui = si[i1];
            float vr = sr[i2], vi = si[i2];
            float tr = vr * wcs - vi * wsn;
            float ti = vr * wsn + vi * wcs;
            sr[i1] = ur + tr; si[i1] = ui + ti;
            sr[i2] = ur - tr; si[i2] = ui - ti;
        }
        __syncthreads();
    }

    // Hermitian unpack: X[m] = E[m] + W^m O[m], W = e^{-2pi i/N}; ortho scale
    const size_t row = (size_t)wg * MP;
    for (int m = tid; m <= H_LEN; m += 256) {
        int ia = m & (H_LEN - 1);
        int ib = (H_LEN - m) & (H_LEN - 1);
        float ar = sr[ia], ai = si[ia];
        float br = sr[ib], bi = si[ib];
        float er = 0.5f * (ar + br), ei = 0.5f * (ai - bi);
        float dr = ar - br, di = ai + bi;
        float or_ = 0.5f * di, oi = -0.5f * dr;
        float ang = -TWO_PI * (float)m * (1.0f / (float)S_LEN);
        float wsn, wcs;
        __sincosf(ang, &wsn, &wcs);
        float xrv = er + wcs * or_ - wsn * oi;
        float xiv = ei + wcs * oi + wsn * or_;
        Xr[row + m] = __float2bfloat16(xrv * INV_SQRT_N);
        Xi[row + m] = __float2bfloat16(xiv * INV_SQRT_N);
    }
}

// ---------------------------------------------------------------------------
// K2: per-mode 2-layer block-diagonal complex MLP, in place over Xr/Xi.
// grid: (mchunks=129, NB, BATCH), block 256. Tile = 32 modes x 96 channels.
// thread -> (mg = tid&7, kg = tid>>3): 4 modes (mg+8j), 3 outputs (kg+32t).
// ---------------------------------------------------------------------------
__global__ __launch_bounds__(256) void mlp_kernel(__hip_bfloat16* __restrict__ Xr,
                                                  __hip_bfloat16* __restrict__ Xi,
                                                  const float* __restrict__ w1,
                                                  const float* __restrict__ b1,
                                                  const float* __restrict__ w2,
                                                  const float* __restrict__ b2) {
    const int TM = 32;
    __shared__ float xr[BLK][TM + 1];
    __shared__ float xi_[BLK][TM + 1];
    __shared__ float o1r[BLK][TM + 1];
    __shared__ float o1i[BLK][TM + 1];

    const int mchunk = blockIdx.x;
    const int n = blockIdx.y;
    const int b = blockIdx.z;
    const int m0 = mchunk * TM;
    int valid = M_LEN - m0;
    if (valid > TM) valid = TM;
    const int tid = threadIdx.x;
    const size_t rowbase = ((size_t)b * HIDDEN + (size_t)n * BLK) * MP + m0;

    // stage input tile
    for (int idx = tid; idx < BLK * TM; idx += 256) {
        int d = idx / TM, mm = idx % TM;
        float vr = 0.f, vi = 0.f;
        if (mm < valid) {
            vr = __bfloat162float(Xr[rowbase + (size_t)d * MP + mm]);
            vi = __bfloat162float(Xi[rowbase + (size_t)d * MP + mm]);
        }
        xr[d][mm] = vr;
        xi_[d][mm] = vi;
    }
    __syncthreads();

    const int mg = tid & 7;
    const int kg = tid >> 3;

    const float* w10 = w1 + (size_t)n * BLK * BLK;
    const float* w11 = w1 + (size_t)(NB + n) * BLK * BLK;

    float ar[3][4], ai_[3][4];
    for (int t = 0; t < 3; t++) {
        int k = kg + 32 * t;
        float brv = b1[n * BLK + k];
        float biv = b1[NB * BLK + n * BLK + k];
        for (int j = 0; j < 4; j++) { ar[t][j] = brv; ai_[t][j] = biv; }
    }
    for (int d = 0; d < BLK; d++) {
        float wa[3], wb[3];
        for (int t = 0; t < 3; t++) {
            wa[t] = w10[d * BLK + kg + 32 * t];
            wb[t] = w11[d * BLK + kg + 32 * t];
        }
        float xrv[4], xiv[4];
        for (int j = 0; j < 4; j++) {
            xrv[j] = xr[d][mg + 8 * j];
            xiv[j] = xi_[d][mg + 8 * j];
        }
        for (int t = 0; t < 3; t++)
            for (int j = 0; j < 4; j++) {
                ar[t][j] = fmaf(xrv[j], wa[t], fmaf(-xiv[j], wb[t], ar[t][j]));
                ai_[t][j] = fmaf(xiv[j], wa[t], fmaf(xrv[j], wb[t], ai_[t][j]));
            }
    }
    // relu -> LDS
    for (int t = 0; t < 3; t++) {
        int k = kg + 32 * t;
        for (int j = 0; j < 4; j++) {
            o1r[k][mg + 8 * j] = fmaxf(ar[t][j], 0.f);
            o1i[k][mg + 8 * j] = fmaxf(ai_[t][j], 0.f);
        }
    }
    __syncthreads();

    // layer 2
    const float* w20 = w2 + (size_t)n * BLK * BLK;
    const float* w21 = w2 + (size_t)(NB + n) * BLK * BLK;
    for (int t = 0; t < 3; t++) {
        int k = kg + 32 * t;
        float brv = b2[n * BLK + k];
        float biv = b2[NB * BLK + n * BLK + k];
        for (int j = 0; j < 4; j++) { ar[t][j] = brv; ai_[t][j] = biv; }
    }
    for (int d = 0; d < BLK; d++) {
        float wa[3], wb[3];
        for (int t = 0; t < 3; t++) {
            wa[t] = w20[d * BLK + kg + 32 * t];
            wb[t] = w21[d * BLK + kg + 32 * t];
        }
        float urv[4], uiv[4];
        for (int j = 0; j < 4; j++) {
            urv[j] = o1r[d][mg + 8 * j];
            uiv[j] = o1i[d][mg + 8 * j];
        }
        for (int t = 0; t < 3; t++)
            for (int j = 0; j < 4; j++) {
                ar[t][j] = fmaf(urv[j], wa[t], fmaf(-uiv[j], wb[t], ar[t][j]));
                ai_[t][j] = fmaf(uiv[j], wa[t], fmaf(urv[j], wb[t], ai_[t][j]));
            }
    }
    // softshrink + in-place write
    for (int t = 0; t < 3; t++) {
        int k = kg + 32 * t;
        size_t rb = rowbase + (size_t)k * MP;
        for (int j = 0; j < 4; j++) {
            int mm = mg + 8 * j;
            if (mm < valid) {
                float vr = ar[t][j], vi = ai_[t][j];
                vr = copysignf(fmaxf(fabsf(vr) - LAM, 0.f), vr);
                vi = copysignf(fmaxf(fabsf(vi) - LAM, 0.f), vi);
                Xr[rb + mm] = __float2bfloat16(vr);
                Xi[rb + mm] = __float2bfloat16(vi);
            }
        }
    }
}

// ---------------------------------------------------------------------------
// K3: inverse rfft per (b,c) + residual add.
// Pack Z[m] = E + iO (ignoring Im(Y0), Im(YH) like numpy irfft), 4096-pt
// inverse FFT, y[2k]=c*Re z, y[2k+1]=c*Im z, + x.
// ---------------------------------------------------------------------------
__global__ __launch_bounds__(256) void fft_inv(const __hip_bfloat16* __restrict__ Yr,
                                               const __hip_bfloat16* __restrict__ Yi,
                                               const float* __restrict__ x,
                                               float* __restrict__ out) {
    __shared__ float sr[H_LEN];
    __shared__ float si[H_LEN];
    const int wg = blockIdx.x;
    const int b = wg / HIDDEN;
    const int c = wg % HIDDEN;
    const int tid = threadIdx.x;
    const size_t row = (size_t)wg * MP;

    for (int m = tid; m < H_LEN; m += 256) {
        float arv = __bfloat162float(Yr[row + m]);
        float aiv = __bfloat162float(Yi[row + m]);
        int m2 = H_LEN - m;  // partner bin (m=0 -> 4096)
        float brv = __bfloat162float(Yr[row + m2]);
        float biv = __bfloat162float(Yi[row + m2]);
        if (m == 0) { aiv = 0.f; biv = 0.f; }  // numpy irfft ignores Im(Y0), Im(YH)
        float er = 0.5f * (arv + brv), ei = 0.5f * (aiv - biv);
        float dr = arv - brv, di = aiv + biv;
        float ang = TWO_PI * (float)m * (1.0f / (float)S_LEN);
        float wsn, wcs;
        __sincosf(ang, &wsn, &wcs);
        float or_ = 0.5f * (wcs * dr - wsn * di);
        float oi = 0.5f * (wcs * di + wsn * dr);
        float zr = er - oi;
        float zi = ei + or_;
        int r = rev12(m);
        sr[r] = zr;
        si[r] = zi;
    }
    __syncthreads();

    // 12 radix-2 DIT stages, inverse (e^{+i}), unnormalized
    for (int len = 2; len <= H_LEN; len <<= 1) {
        const int half = len >> 1;
        const float inv_len = 1.0f / (float)len;
        for (int i = tid; i < H_LEN / 2; i += 256) {
            int j = i & (half - 1);
            int i1 = ((i - j) << 1) + j;
            int i2 = i1 + half;
            float ang = TWO_PI * (float)j * inv_len;
            float wsn, wcs;
            __sincosf(ang, &wsn, &wcs);
            float ur = sr[i1], ui = si[i1];
            float vr = sr[i2], vi = si[i2];
            float tr = vr * wcs - vi * wsn;
            float ti = vr * wsn + vi * wcs;
            sr[i1] = ur + tr; si[i1] = ui + ti;
            sr[i2] = ur - tr; si[i2] = ui - ti;
        }
        __syncthreads();
    }

    const float* xb = x + (size_t)b * S_LEN * HIDDEN + c;
    float* ob = out + (size_t)b * S_LEN * HIDDEN + c;
    for (int k = tid; k < H_LEN; k += 256) {
        ob[(size_t)(2 * k) * HIDDEN] =
            fmaf(C_INV, sr[k], xb[(size_t)(2 * k) * HIDDEN]);
        ob[(size_t)(2 * k + 1) * HIDDEN] =
            fmaf(C_INV, si[k], xb[(size_t)(2 * k + 1) * HIDDEN]);
    }
}

// ---------------------------------------------------------------------------
extern "C" void kernel_launch(void* const* d_in, const int* in_sizes, int n_in,
                              void* d_out, int out_size, void* d_ws, size_t ws_size,
                              hipStream_t stream) {
    const float* x  = (const float*)d_in[0];
    const float* w1 = (const float*)d_in[1];
    const float* b1 = (const float*)d_in[2];
    const float* w2 = (const float*)d_in[3];
    const float* b2 = (const float*)d_in[4];
    float* out = (float*)d_out;

    __hip_bfloat16* Xr = (__hip_bfloat16*)d_ws;
    __hip_bfloat16* Xi = Xr + (size_t)BATCH * HIDDEN * MP;

    fft_fwd<<<BATCH * HIDDEN, 256, 0, stream>>>(x, Xr, Xi);

    const int mchunks = (M_LEN + 31) / 32;  // 129
    mlp_kernel<<<dim3(mchunks, NB, BATCH), 256, 0, stream>>>(Xr, Xi, w1, b1, w2, b2);

    fft_inv<<<BATCH * HIDDEN, 256, 0, stream>>>(Xr, Xi, x, out);
}

// Round 2
// 688.099 us; speedup vs baseline: 1.9006x; 1.9006x over previous
//
#include <hip/hip_runtime.h>
#include <hip/hip_bf16.h>

#define HIDDEN 768
#define NB 8
#define BLK 96
#define S_LEN 8192
#define H_LEN 4096
#define M_LEN 4097
#define MP 4104          // padded spectrum row pitch
#define BATCH 4

#define TWO_PI 6.28318530717958647692f
#define INV_SQRT_N 0.011048543456039806f   // 1/sqrt(8192)
#define C_INV 0.022097086912079612f        // 2/sqrt(8192)
#define LAM 0.01f

__device__ __forceinline__ int rev12(int k) {
    return (int)(__brev((unsigned)k) >> 20);
}

// ---------------------------------------------------------------------------
// K0: x [B,S,C] f32  ->  xT [B*C, S] bf16   (32x32 LDS tiles, coalesced)
// ---------------------------------------------------------------------------
__global__ __launch_bounds__(256) void transpose_in(const float* __restrict__ x,
                                                    __hip_bfloat16* __restrict__ xT) {
    __shared__ float t[32][33];
    const int cb = blockIdx.x, sb = blockIdx.y, b = blockIdx.z;
    const int tx = threadIdx.x & 31, ty = threadIdx.x >> 5;
    const float* xp = x + ((size_t)b * S_LEN + sb * 32) * HIDDEN + cb * 32;
    for (int i = 0; i < 4; i++)
        t[ty + 8 * i][tx] = xp[(size_t)(ty + 8 * i) * HIDDEN + tx];
    __syncthreads();
    __hip_bfloat16* xq = xT + ((size_t)b * HIDDEN + cb * 32) * S_LEN + sb * 32;
    for (int i = 0; i < 4; i++)
        xq[(size_t)(ty + 8 * i) * S_LEN + tx] = __float2bfloat16(t[tx][ty + 8 * i]);
}

// ---------------------------------------------------------------------------
// K1: forward rfft per (b,c). Reads contiguous bf16 row; bit-reversal scatter
// remapped so LDS write bank = rev5(tid&31) -> 2-way (free).
// ---------------------------------------------------------------------------
__global__ __launch_bounds__(256) void fft_fwd(const __hip_bfloat16* __restrict__ xT,
                                               __hip_bfloat16* __restrict__ Xr,
                                               __hip_bfloat16* __restrict__ Xi) {
    __shared__ float sr[H_LEN];
    __shared__ float si[H_LEN];
    const int wg = blockIdx.x;           // b*HIDDEN + c
    const int tid = threadIdx.x;
    const __hip_bfloat162* xrow = (const __hip_bfloat162*)(xT + (size_t)wg * S_LEN);

    const int a = tid & 31, cb3 = tid >> 5;
    for (int it = 0; it < 16; it++) {
        int k = (a << 7) | (it << 3) | cb3;        // bijective over [0,4096)
        __hip_bfloat162 v = xrow[k];               // z[k] = x[2k] + i x[2k+1]
        int r = rev12(k);                          // bank = rev5(a): conflict-free
        sr[r] = __bfloat162float(v.x);
        si[r] = __bfloat162float(v.y);
    }
    __syncthreads();

    // 12 radix-2 DIT stages, forward (e^{-i})
    for (int len = 2; len <= H_LEN; len <<= 1) {
        const int half = len >> 1;
        const float inv_len = 1.0f / (float)len;
        for (int i = tid; i < H_LEN / 2; i += 256) {
            int j = i & (half - 1);
            int i1 = ((i - j) << 1) + j;
            int i2 = i1 + half;
            float ang = -TWO_PI * (float)j * inv_len;
            float wsn, wcs;
            __sincosf(ang, &wsn, &wcs);
            float ur = sr[i1], ui = si[i1];
            float vr = sr[i2], vi = si[i2];
            float tr = vr * wcs - vi * wsn;
            float ti = vr * wsn + vi * wcs;
            sr[i1] = ur + tr; si[i1] = ui + ti;
            sr[i2] = ur - tr; si[i2] = ui - ti;
        }
        __syncthreads();
    }

    // Hermitian unpack: X[m] = E[m] + W^m O[m]; ortho scale; coalesced store
    const size_t row = (size_t)wg * MP;
    for (int m = tid; m <= H_LEN; m += 256) {
        int ia = m & (H_LEN - 1);
        int ib = (H_LEN - m) & (H_LEN - 1);
        float ar = sr[ia], ai = si[ia];
        float br = sr[ib], bi = si[ib];
        float er = 0.5f * (ar + br), ei = 0.5f * (ai - bi);
        float dr = ar - br, di = ai + bi;
        float or_ = 0.5f * di, oi = -0.5f * dr;
        float ang = -TWO_PI * (float)m * (1.0f / (float)S_LEN);
        float wsn, wcs;
        __sincosf(ang, &wsn, &wcs);
        float xrv = er + wcs * or_ - wsn * oi;
        float xiv = ei + wcs * oi + wsn * or_;
        Xr[row + m] = __float2bfloat16(xrv * INV_SQRT_N);
        Xi[row + m] = __float2bfloat16(xiv * INV_SQRT_N);
    }
}

// ---------------------------------------------------------------------------
// K2: per-mode 2-layer block-diagonal complex MLP, in place over Xr/Xi.
// ---------------------------------------------------------------------------
__global__ __launch_bounds__(256) void mlp_kernel(__hip_bfloat16* __restrict__ Xr,
                                                  __hip_bfloat16* __restrict__ Xi,
                                                  const float* __restrict__ w1,
                                                  const float* __restrict__ b1,
                                                  const float* __restrict__ w2,
                                                  const float* __restrict__ b2) {
    const int TM = 32;
    __shared__ float xr[BLK][TM + 1];
    __shared__ float xi_[BLK][TM + 1];
    __shared__ float o1r[BLK][TM + 1];
    __shared__ float o1i[BLK][TM + 1];

    const int mchunk = blockIdx.x;
    const int n = blockIdx.y;
    const int b = blockIdx.z;
    const int m0 = mchunk * TM;
    int valid = M_LEN - m0;
    if (valid > TM) valid = TM;
    const int tid = threadIdx.x;
    const size_t rowbase = ((size_t)b * HIDDEN + (size_t)n * BLK) * MP + m0;

    for (int idx = tid; idx < BLK * TM; idx += 256) {
        int d = idx / TM, mm = idx % TM;
        float vr = 0.f, vi = 0.f;
        if (mm < valid) {
            vr = __bfloat162float(Xr[rowbase + (size_t)d * MP + mm]);
            vi = __bfloat162float(Xi[rowbase + (size_t)d * MP + mm]);
        }
        xr[d][mm] = vr;
        xi_[d][mm] = vi;
    }
    __syncthreads();

    const int mg = tid & 7;
    const int kg = tid >> 3;

    const float* w10 = w1 + (size_t)n * BLK * BLK;
    const float* w11 = w1 + (size_t)(NB + n) * BLK * BLK;

    float ar[3][4], ai_[3][4];
    for (int t = 0; t < 3; t++) {
        int k = kg + 32 * t;
        float brv = b1[n * BLK + k];
        float biv = b1[NB * BLK + n * BLK + k];
        for (int j = 0; j < 4; j++) { ar[t][j] = brv; ai_[t][j] = biv; }
    }
    for (int d = 0; d < BLK; d++) {
        float wa[3], wb[3];
        for (int t = 0; t < 3; t++) {
            wa[t] = w10[d * BLK + kg + 32 * t];
            wb[t] = w11[d * BLK + kg + 32 * t];
        }
        float xrv[4], xiv[4];
        for (int j = 0; j < 4; j++) {
            xrv[j] = xr[d][mg + 8 * j];
            xiv[j] = xi_[d][mg + 8 * j];
        }
        for (int t = 0; t < 3; t++)
            for (int j = 0; j < 4; j++) {
                ar[t][j] = fmaf(xrv[j], wa[t], fmaf(-xiv[j], wb[t], ar[t][j]));
                ai_[t][j] = fmaf(xiv[j], wa[t], fmaf(xrv[j], wb[t], ai_[t][j]));
            }
    }
    for (int t = 0; t < 3; t++) {
        int k = kg + 32 * t;
        for (int j = 0; j < 4; j++) {
            o1r[k][mg + 8 * j] = fmaxf(ar[t][j], 0.f);
            o1i[k][mg + 8 * j] = fmaxf(ai_[t][j], 0.f);
        }
    }
    __syncthreads();

    const float* w20 = w2 + (size_t)n * BLK * BLK;
    const float* w21 = w2 + (size_t)(NB + n) * BLK * BLK;
    for (int t = 0; t < 3; t++) {
        int k = kg + 32 * t;
        float brv = b2[n * BLK + k];
        float biv = b2[NB * BLK + n * BLK + k];
        for (int j = 0; j < 4; j++) { ar[t][j] = brv; ai_[t][j] = biv; }
    }
    for (int d = 0; d < BLK; d++) {
        float wa[3], wb[3];
        for (int t = 0; t < 3; t++) {
            wa[t] = w20[d * BLK + kg + 32 * t];
            wb[t] = w21[d * BLK + kg + 32 * t];
        }
        float urv[4], uiv[4];
        for (int j = 0; j < 4; j++) {
            urv[j] = o1r[d][mg + 8 * j];
            uiv[j] = o1i[d][mg + 8 * j];
        }
        for (int t = 0; t < 3; t++)
            for (int j = 0; j < 4; j++) {
                ar[t][j] = fmaf(urv[j], wa[t], fmaf(-uiv[j], wb[t], ar[t][j]));
                ai_[t][j] = fmaf(uiv[j], wa[t], fmaf(urv[j], wb[t], ai_[t][j]));
            }
    }
    for (int t = 0; t < 3; t++) {
        int k = kg + 32 * t;
        size_t rb = rowbase + (size_t)k * MP;
        for (int j = 0; j < 4; j++) {
            int mm = mg + 8 * j;
            if (mm < valid) {
                float vr = ar[t][j], vi = ai_[t][j];
                vr = copysignf(fmaxf(fabsf(vr) - LAM, 0.f), vr);
                vi = copysignf(fmaxf(fabsf(vi) - LAM, 0.f), vi);
                Xr[rb + mm] = __float2bfloat16(vr);
                Xi[rb + mm] = __float2bfloat16(vi);
            }
        }
    }
}

// ---------------------------------------------------------------------------
// K3: inverse rfft per (b,c), writes yT [B*C, S] bf16 (no residual here).
// Same conflict-free bit-reversal mapping; global side is an L1-resident gather.
// ---------------------------------------------------------------------------
__global__ __launch_bounds__(256) void fft_inv(const __hip_bfloat16* __restrict__ Yr,
                                               const __hip_bfloat16* __restrict__ Yi,
                                               __hip_bfloat16* __restrict__ yT) {
    __shared__ float sr[H_LEN];
    __shared__ float si[H_LEN];
    const int wg = blockIdx.x;
    const int tid = threadIdx.x;
    const size_t row = (size_t)wg * MP;

    const int a = tid & 31, cb3 = tid >> 5;
    for (int it = 0; it < 16; it++) {
        int m = (a << 7) | (it << 3) | cb3;
        float arv = __bfloat162float(Yr[row + m]);
        float aiv = __bfloat162float(Yi[row + m]);
        int m2 = H_LEN - m;                      // partner (m=0 -> 4096)
        float brv = __bfloat162float(Yr[row + m2]);
        float biv = __bfloat162float(Yi[row + m2]);
        if (m == 0) { aiv = 0.f; biv = 0.f; }    // numpy irfft drops Im(Y0), Im(YH)
        float er = 0.5f * (arv + brv), ei = 0.5f * (aiv - biv);
        float dr = arv - brv, di = aiv + biv;
        float ang = TWO_PI * (float)m * (1.0f / (float)S_LEN);
        float wsn, wcs;
        __sincosf(ang, &wsn, &wcs);
        float or_ = 0.5f * (wcs * dr - wsn * di);
        float oi = 0.5f * (wcs * di + wsn * dr);
        int r = rev12(m);
        sr[r] = er - oi;
        si[r] = ei + or_;
    }
    __syncthreads();

    for (int len = 2; len <= H_LEN; len <<= 1) {
        const int half = len >> 1;
        const float inv_len = 1.0f / (float)len;
        for (int i = tid; i < H_LEN / 2; i += 256) {
            int j = i & (half - 1);
            int i1 = ((i - j) << 1) + j;
            int i2 = i1 + half;
            float ang = TWO_PI * (float)j * inv_len;
            float wsn, wcs;
            __sincosf(ang, &wsn, &wcs);
            float ur = sr[i1], ui = si[i1];
            float vr = sr[i2], vi = si[i2];
            float tr = vr * wcs - vi * wsn;
            float ti = vr * wsn + vi * wcs;
            sr[i1] = ur + tr; si[i1] = ui + ti;
            sr[i2] = ur - tr; si[i2] = ui - ti;
        }
        __syncthreads();
    }

    __hip_bfloat162* orow = (__hip_bfloat162*)(yT + (size_t)wg * S_LEN);
    for (int k = tid; k < H_LEN; k += 256) {
        __hip_bfloat162 v;
        v.x = __float2bfloat16(C_INV * sr[k]);
        v.y = __float2bfloat16(C_INV * si[k]);
        orow[k] = v;
    }
}

// ---------------------------------------------------------------------------
// K4: out[b,s,c] = x[b,s,c] + yT[b*C+c, s]   (transpose back + residual)
// ---------------------------------------------------------------------------
__global__ __launch_bounds__(256) void add_out(const __hip_bfloat16* __restrict__ yT,
                                               const float* __restrict__ x,
                                               float* __restrict__ out) {
    __shared__ float t[32][33];
    const int cb = blockIdx.x, sb = blockIdx.y, b = blockIdx.z;
    const int tx = threadIdx.x & 31, ty = threadIdx.x >> 5;
    const __hip_bfloat16* yp = yT + ((size_t)b * HIDDEN + cb * 32) * S_LEN + sb * 32;
    for (int i = 0; i < 4; i++)
        t[ty + 8 * i][tx] = __bfloat162float(yp[(size_t)(ty + 8 * i) * S_LEN + tx]);
    __syncthreads();
    const size_t off = ((size_t)b * S_LEN + sb * 32) * HIDDEN + cb * 32;
    const float* xp = x + off;
    float* op = out + off;
    for (int i = 0; i < 4; i++)
        op[(size_t)(ty + 8 * i) * HIDDEN + tx] =
            xp[(size_t)(ty + 8 * i) * HIDDEN + tx] + t[tx][ty + 8 * i];
}

// ---------------------------------------------------------------------------
extern "C" void kernel_launch(void* const* d_in, const int* in_sizes, int n_in,
                              void* d_out, int out_size, void* d_ws, size_t ws_size,
                              hipStream_t stream) {
    const float* x  = (const float*)d_in[0];
    const float* w1 = (const float*)d_in[1];
    const float* b1 = (const float*)d_in[2];
    const float* w2 = (const float*)d_in[3];
    const float* b2 = (const float*)d_in[4];
    float* out = (float*)d_out;

    // ws layout: xT/yT (reused) bf16 [B*C, S] = 50.3 MB, spectrum 50.4 MB
    __hip_bfloat16* xT = (__hip_bfloat16*)d_ws;
    __hip_bfloat16* Xr = xT + (size_t)BATCH * HIDDEN * S_LEN;
    __hip_bfloat16* Xi = Xr + (size_t)BATCH * HIDDEN * MP;

    transpose_in<<<dim3(HIDDEN / 32, S_LEN / 32, BATCH), 256, 0, stream>>>(x, xT);

    fft_fwd<<<BATCH * HIDDEN, 256, 0, stream>>>(xT, Xr, Xi);

    const int mchunks = (M_LEN + 31) / 32;  // 129
    mlp_kernel<<<dim3(mchunks, NB, BATCH), 256, 0, stream>>>(Xr, Xi, w1, b1, w2, b2);

    fft_inv<<<BATCH * HIDDEN, 256, 0, stream>>>(Xr, Xi, xT /* as yT */);

    add_out<<<dim3(HIDDEN / 32, S_LEN / 32, BATCH), 256, 0, stream>>>(xT, x, out);
}

// Round 3
// 445.418 us; speedup vs baseline: 2.9362x; 1.5448x over previous
//
#include <hip/hip_runtime.h>
#include <hip/hip_bf16.h>

#define HIDDEN 768
#define NB 8
#define BLK 96
#define S_LEN 8192
#define H_LEN 4096
#define M_LEN 4097
#define MP 4160           // spectrum word pitch (65*64); one (r,i) bf16 word per mode
#define BATCH 4
#define KBIG 192          // 2*BLK (interleaved r/i channels)
#define TMOD 64           // modes per MLP workgroup
#define MPITCH 66         // act LDS row pitch in bf16 elems (33 words, odd -> conflict-free)

#define TWO_PI 6.28318530717958647692f
#define INV_SQRT_N 0.011048543456039806f   // 1/sqrt(8192)
#define C_INV 0.022097086912079612f        // 2/sqrt(8192)
#define LAM 0.01f

typedef __attribute__((ext_vector_type(8))) short short8;
typedef __attribute__((ext_vector_type(4))) float float4v;

__device__ __forceinline__ int rev12(int k) {
    return (int)(__brev((unsigned)k) >> 20);
}
__device__ __forceinline__ short f2bf(float f) {
    __hip_bfloat16 h = __float2bfloat16(f);
    return *reinterpret_cast<short*>(&h);
}
__device__ __forceinline__ float bf2f(unsigned short s) {
    __hip_bfloat16 h = *reinterpret_cast<__hip_bfloat16*>(&s);
    return __bfloat162float(h);
}

// ---------------------------------------------------------------------------
// P0: build bf16 big-weight matrices WT[n][out=192][kin=192] (kin interleaved
// r/i) for both layers, plus concatenated biases (fp32).
//   layer out cols = [o_r(96) | o_i(96)];  kin even = r_d, kin odd = i_d.
// ---------------------------------------------------------------------------
__global__ __launch_bounds__(256) void prep_weights(const float* __restrict__ w1,
                                                    const float* __restrict__ w2,
                                                    const float* __restrict__ b1,
                                                    const float* __restrict__ b2,
                                                    short* __restrict__ WT1,
                                                    short* __restrict__ WT2,
                                                    float* __restrict__ bb1,
                                                    float* __restrict__ bb2) {
    int idx = blockIdx.x * 256 + threadIdx.x;
    if (idx < NB * KBIG * KBIG) {
        int n = idx / (KBIG * KBIG);
        int r = idx % (KBIG * KBIG);
        int o = r / KBIG;
        int kin = r % KBIG;
        int d = kin >> 1;
        int im = kin & 1;
        {
            float w0 = w1[((size_t)(0 * NB + n) * BLK + d) * BLK + (o < BLK ? o : o - BLK)];
            float wi = w1[((size_t)(1 * NB + n) * BLK + d) * BLK + (o < BLK ? o : o - BLK)];
            float v = (o < BLK) ? (im ? -wi : w0) : (im ? w0 : wi);
            WT1[idx] = f2bf(v);
        }
        {
            float w0 = w2[((size_t)(0 * NB + n) * BLK + d) * BLK + (o < BLK ? o : o - BLK)];
            float wi = w2[((size_t)(1 * NB + n) * BLK + d) * BLK + (o < BLK ? o : o - BLK)];
            float v = (o < BLK) ? (im ? -wi : w0) : (im ? w0 : wi);
            WT2[idx] = f2bf(v);
        }
    }
    if (idx < NB * KBIG) {
        int n = idx / KBIG, o = idx % KBIG;
        bb1[idx] = (o < BLK) ? b1[(0 * NB + n) * BLK + o] : b1[(1 * NB + n) * BLK + o - BLK];
        bb2[idx] = (o < BLK) ? b2[(0 * NB + n) * BLK + o] : b2[(1 * NB + n) * BLK + o - BLK];
    }
}

// ---------------------------------------------------------------------------
// K0: x [B,S,C] f32  ->  xT [B*C, S] bf16   (32x32 LDS tiles, coalesced)
// ---------------------------------------------------------------------------
__global__ __launch_bounds__(256) void transpose_in(const float* __restrict__ x,
                                                    __hip_bfloat16* __restrict__ xT) {
    __shared__ float t[32][33];
    const int cb = blockIdx.x, sb = blockIdx.y, b = blockIdx.z;
    const int tx = threadIdx.x & 31, ty = threadIdx.x >> 5;
    const float* xp = x + ((size_t)b * S_LEN + sb * 32) * HIDDEN + cb * 32;
    for (int i = 0; i < 4; i++)
        t[ty + 8 * i][tx] = xp[(size_t)(ty + 8 * i) * HIDDEN + tx];
    __syncthreads();
    __hip_bfloat16* xq = xT + ((size_t)b * HIDDEN + cb * 32) * S_LEN + sb * 32;
    for (int i = 0; i < 4; i++)
        xq[(size_t)(ty + 8 * i) * S_LEN + tx] = __float2bfloat16(t[tx][ty + 8 * i]);
}

// ---------------------------------------------------------------------------
// K1: forward rfft per (b,c) -> interleaved (r,i) bf16 words Xc[row][m]
// ---------------------------------------------------------------------------
__global__ __launch_bounds__(256) void fft_fwd(const __hip_bfloat16* __restrict__ xT,
                                               unsigned int* __restrict__ Xc) {
    __shared__ float sr[H_LEN];
    __shared__ float si[H_LEN];
    const int wg = blockIdx.x;           // b*HIDDEN + c
    const int tid = threadIdx.x;
    const __hip_bfloat162* xrow = (const __hip_bfloat162*)(xT + (size_t)wg * S_LEN);

    const int a = tid & 31, cb3 = tid >> 5;
    for (int it = 0; it < 16; it++) {
        int k = (a << 7) | (it << 3) | cb3;        // bijective over [0,4096)
        __hip_bfloat162 v = xrow[k];               // z[k] = x[2k] + i x[2k+1]
        int r = rev12(k);                          // bank = rev5(a): conflict-free
        sr[r] = __bfloat162float(v.x);
        si[r] = __bfloat162float(v.y);
    }
    __syncthreads();

    for (int len = 2; len <= H_LEN; len <<= 1) {
        const int half = len >> 1;
        const float inv_len = 1.0f / (float)len;
        for (int i = tid; i < H_LEN / 2; i += 256) {
            int j = i & (half - 1);
            int i1 = ((i - j) << 1) + j;
            int i2 = i1 + half;
            float ang = -TWO_PI * (float)j * inv_len;
            float wsn, wcs;
            __sincosf(ang, &wsn, &wcs);
            float ur = sr[i1], ui = si[i1];
            float vr = sr[i2], vi = si[i2];
            float tr = vr * wcs - vi * wsn;
            float ti = vr * wsn + vi * wcs;
            sr[i1] = ur + tr; si[i1] = ui + ti;
            sr[i2] = ur - tr; si[i2] = ui - ti;
        }
        __syncthreads();
    }

    unsigned int* Xrow = Xc + (size_t)wg * MP;
    for (int m = tid; m <= H_LEN; m += 256) {
        int ia = m & (H_LEN - 1);
        int ib = (H_LEN - m) & (H_LEN - 1);
        float ar = sr[ia], ai = si[ia];
        float br = sr[ib], bi = si[ib];
        float er = 0.5f * (ar + br), ei = 0.5f * (ai - bi);
        float dr = ar - br, di = ai + bi;
        float or_ = 0.5f * di, oi = -0.5f * dr;
        float ang = -TWO_PI * (float)m * (1.0f / (float)S_LEN);
        float wsn, wcs;
        __sincosf(ang, &wsn, &wcs);
        float xrv = (er + wcs * or_ - wsn * oi) * INV_SQRT_N;
        float xiv = (ei + wcs * oi + wsn * or_) * INV_SQRT_N;
        unsigned wd = (unsigned short)f2bf(xrv) | ((unsigned)(unsigned short)f2bf(xiv) << 16);
        Xrow[m] = wd;
    }
}

// ---------------------------------------------------------------------------
// K2: MFMA block-diagonal complex MLP, in place over Xc.
// A = WT (registers), B = activations LDS [k][mode], D = [out][mode].
// grid (65 mode-chunks, NB, BATCH), 256 thr = 4 waves; wave w owns outs 48w..48w+47.
// ---------------------------------------------------------------------------
__global__ __launch_bounds__(256) void mlp_mfma(const short* __restrict__ WT1,
                                                const short* __restrict__ WT2,
                                                const float* __restrict__ bb1,
                                                const float* __restrict__ bb2,
                                                unsigned int* __restrict__ Xc) {
    __shared__ short actA[KBIG * MPITCH];  // input, later final output
    __shared__ short actB[KBIG * MPITCH];  // layer-1 output
    const int tid = threadIdx.x;
    const int chunk = blockIdx.x;          // 0..64
    const int n = blockIdx.y;
    const int b = blockIdx.z;
    const int m0 = chunk * TMOD;
    unsigned int* __restrict__ Xrow0 =
        Xc + ((size_t)b * HIDDEN + (size_t)n * BLK) * MP + m0;

    // ---- stage: 96 channel rows x 64 modes, de-interleave to rows 2d / 2d+1
    {
        const int mw = tid & 31;           // word-pair: modes 2mw, 2mw+1
        const int dr = tid >> 5;           // 0..7
        int* a32 = (int*)actA;
        for (int pass = 0; pass < 12; pass++) {
            int d = dr + pass * 8;
            const uint2* src = (const uint2*)(Xrow0 + (size_t)d * MP);
            uint2 v = src[mw];
            unsigned rw = (v.x & 0xFFFFu) | (v.y << 16);
            unsigned iw = (v.x >> 16) | (v.y & 0xFFFF0000u);
            a32[(2 * d) * 33 + mw] = (int)rw;
            a32[(2 * d + 1) * 33 + mw] = (int)iw;
        }
    }
    __syncthreads();

    const int w = tid >> 6;
    const int l15 = tid & 15;
    const int q = (tid >> 4) & 3;
    const int outw = w * 48;

    // ---- layer 1 ----
    short8 wf[3][6];
    for (int nl = 0; nl < 3; nl++)
        for (int ks = 0; ks < 6; ks++)
            wf[nl][ks] = *(const short8*)(WT1 + ((size_t)n * KBIG + outw + nl * 16 + l15) * KBIG + ks * 32 + q * 8);

    for (int mt = 0; mt < 4; mt++) {
        float4v acc[3];
        for (int nl = 0; nl < 3; nl++)
            acc[nl] = *(const float4v*)(bb1 + n * KBIG + outw + nl * 16 + q * 4);
        for (int ks = 0; ks < 6; ks++) {
            short8 bf;
            const short* base = actA + (ks * 32 + q * 8) * MPITCH + mt * 16 + l15;
            #pragma unroll
            for (int j = 0; j < 8; j++) bf[j] = base[j * MPITCH];
            acc[0] = __builtin_amdgcn_mfma_f32_16x16x32_bf16(wf[0][ks], bf, acc[0], 0, 0, 0);
            acc[1] = __builtin_amdgcn_mfma_f32_16x16x32_bf16(wf[1][ks], bf, acc[1], 0, 0, 0);
            acc[2] = __builtin_amdgcn_mfma_f32_16x16x32_bf16(wf[2][ks], bf, acc[2], 0, 0, 0);
        }
        for (int nl = 0; nl < 3; nl++)
            #pragma unroll
            for (int reg = 0; reg < 4; reg++) {
                int out = outw + nl * 16 + q * 4 + reg;
                int row = (out < BLK) ? (out << 1) : (((out - BLK) << 1) | 1);
                actB[row * MPITCH + mt * 16 + l15] = f2bf(fmaxf(acc[nl][reg], 0.f));
            }
    }
    __syncthreads();

    // ---- layer 2 ----
    short8 wf2[3][6];
    for (int nl = 0; nl < 3; nl++)
        for (int ks = 0; ks < 6; ks++)
            wf2[nl][ks] = *(const short8*)(WT2 + ((size_t)n * KBIG + outw + nl * 16 + l15) * KBIG + ks * 32 + q * 8);

    for (int mt = 0; mt < 4; mt++) {
        float4v acc[3];
        for (int nl = 0; nl < 3; nl++)
            acc[nl] = *(const float4v*)(bb2 + n * KBIG + outw + nl * 16 + q * 4);
        for (int ks = 0; ks < 6; ks++) {
            short8 bf;
            const short* base = actB + (ks * 32 + q * 8) * MPITCH + mt * 16 + l15;
            #pragma unroll
            for (int j = 0; j < 8; j++) bf[j] = base[j * MPITCH];
            acc[0] = __builtin_amdgcn_mfma_f32_16x16x32_bf16(wf2[0][ks], bf, acc[0], 0, 0, 0);
            acc[1] = __builtin_amdgcn_mfma_f32_16x16x32_bf16(wf2[1][ks], bf, acc[1], 0, 0, 0);
            acc[2] = __builtin_amdgcn_mfma_f32_16x16x32_bf16(wf2[2][ks], bf, acc[2], 0, 0, 0);
        }
        for (int nl = 0; nl < 3; nl++)
            #pragma unroll
            for (int reg = 0; reg < 4; reg++) {
                int out = outw + nl * 16 + q * 4 + reg;
                float v = acc[nl][reg];
                v = copysignf(fmaxf(fabsf(v) - LAM, 0.f), v);
                actA[out * MPITCH + mt * 16 + l15] = f2bf(v);
            }
    }
    __syncthreads();

    // ---- write back: re-interleave rows d (r) and d+96 (i) into words
    {
        const int m = tid & 63;
        const int dr = tid >> 6;          // 0..3
        for (int pass = 0; pass < 24; pass++) {
            int d = dr + pass * 4;
            unsigned short rv = (unsigned short)actA[d * MPITCH + m];
            unsigned short iv = (unsigned short)actA[(d + BLK) * MPITCH + m];
            Xrow0[(size_t)d * MP + m] = (unsigned)rv | ((unsigned)iv << 16);
        }
    }
}

// ---------------------------------------------------------------------------
// K3: inverse rfft per (b,c): Xc -> yT [B*C, S] bf16
// ---------------------------------------------------------------------------
__global__ __launch_bounds__(256) void fft_inv(const unsigned int* __restrict__ Xc,
                                               __hip_bfloat16* __restrict__ yT) {
    __shared__ float sr[H_LEN];
    __shared__ float si[H_LEN];
    const int wg = blockIdx.x;
    const int tid = threadIdx.x;
    const unsigned int* Xrow = Xc + (size_t)wg * MP;

    const int a = tid & 31, cb3 = tid >> 5;
    for (int it = 0; it < 16; it++) {
        int m = (a << 7) | (it << 3) | cb3;
        unsigned va = Xrow[m];
        int m2 = H_LEN - m;                       // partner (m=0 -> 4096)
        unsigned vb = Xrow[m2];
        float arv = bf2f((unsigned short)(va & 0xFFFF));
        float aiv = bf2f((unsigned short)(va >> 16));
        float brv = bf2f((unsigned short)(vb & 0xFFFF));
        float biv = bf2f((unsigned short)(vb >> 16));
        if (m == 0) { aiv = 0.f; biv = 0.f; }     // numpy irfft drops Im(Y0), Im(YH)
        float er = 0.5f * (arv + brv), ei = 0.5f * (aiv - biv);
        float dr = arv - brv, di = aiv + biv;
        float ang = TWO_PI * (float)m * (1.0f / (float)S_LEN);
        float wsn, wcs;
        __sincosf(ang, &wsn, &wcs);
        float or_ = 0.5f * (wcs * dr - wsn * di);
        float oi = 0.5f * (wcs * di + wsn * dr);
        int r = rev12(m);
        sr[r] = er - oi;
        si[r] = ei + or_;
    }
    __syncthreads();

    for (int len = 2; len <= H_LEN; len <<= 1) {
        const int half = len >> 1;
        const float inv_len = 1.0f / (float)len;
        for (int i = tid; i < H_LEN / 2; i += 256) {
            int j = i & (half - 1);
            int i1 = ((i - j) << 1) + j;
            int i2 = i1 + half;
            float ang = TWO_PI * (float)j * inv_len;
            float wsn, wcs;
            __sincosf(ang, &wsn, &wcs);
            float ur = sr[i1], ui = si[i1];
            float vr = sr[i2], vi = si[i2];
            float tr = vr * wcs - vi * wsn;
            float ti = vr * wsn + vi * wcs;
            sr[i1] = ur + tr; si[i1] = ui + ti;
            sr[i2] = ur - tr; si[i2] = ui - ti;
        }
        __syncthreads();
    }

    __hip_bfloat162* orow = (__hip_bfloat162*)(yT + (size_t)wg * S_LEN);
    for (int k = tid; k < H_LEN; k += 256) {
        __hip_bfloat162 v;
        v.x = __float2bfloat16(C_INV * sr[k]);
        v.y = __float2bfloat16(C_INV * si[k]);
        orow[k] = v;
    }
}

// ---------------------------------------------------------------------------
// K4: out[b,s,c] = x[b,s,c] + yT[b*C+c, s]
// ---------------------------------------------------------------------------
__global__ __launch_bounds__(256) void add_out(const __hip_bfloat16* __restrict__ yT,
                                               const float* __restrict__ x,
                                               float* __restrict__ out) {
    __shared__ float t[32][33];
    const int cb = blockIdx.x, sb = blockIdx.y, b = blockIdx.z;
    const int tx = threadIdx.x & 31, ty = threadIdx.x >> 5;
    const __hip_bfloat16* yp = yT + ((size_t)b * HIDDEN + cb * 32) * S_LEN + sb * 32;
    for (int i = 0; i < 4; i++)
        t[ty + 8 * i][tx] = __bfloat162float(yp[(size_t)(ty + 8 * i) * S_LEN + tx]);
    __syncthreads();
    const size_t off = ((size_t)b * S_LEN + sb * 32) * HIDDEN + cb * 32;
    const float* xp = x + off;
    float* op = out + off;
    for (int i = 0; i < 4; i++)
        op[(size_t)(ty + 8 * i) * HIDDEN + tx] =
            xp[(size_t)(ty + 8 * i) * HIDDEN + tx] + t[tx][ty + 8 * i];
}

// ---------------------------------------------------------------------------
extern "C" void kernel_launch(void* const* d_in, const int* in_sizes, int n_in,
                              void* d_out, int out_size, void* d_ws, size_t ws_size,
                              hipStream_t stream) {
    const float* x  = (const float*)d_in[0];
    const float* w1 = (const float*)d_in[1];
    const float* b1 = (const float*)d_in[2];
    const float* w2 = (const float*)d_in[3];
    const float* b2 = (const float*)d_in[4];
    float* out = (float*)d_out;

    // ws layout (all 16B-aligned):
    //   xT/yT  bf16 [B*C, S]              50.33 MB
    //   Xc     u32  [B*C, MP]             51.12 MB
    //   WT1/WT2 bf16 [NB,192,192]         2x0.59 MB
    //   bb1/bb2 f32 [NB,192]              2x6 KB
    char* p = (char*)d_ws;
    __hip_bfloat16* xT = (__hip_bfloat16*)p;           p += (size_t)BATCH * HIDDEN * S_LEN * 2;
    unsigned int*   Xc = (unsigned int*)p;             p += (size_t)BATCH * HIDDEN * MP * 4;
    short* WT1 = (short*)p;                            p += (size_t)NB * KBIG * KBIG * 2;
    short* WT2 = (short*)p;                            p += (size_t)NB * KBIG * KBIG * 2;
    float* bb1 = (float*)p;                            p += (size_t)NB * KBIG * 4;
    float* bb2 = (float*)p;

    prep_weights<<<(NB * KBIG * KBIG + 255) / 256, 256, 0, stream>>>(
        w1, w2, b1, b2, WT1, WT2, bb1, bb2);

    transpose_in<<<dim3(HIDDEN / 32, S_LEN / 32, BATCH), 256, 0, stream>>>(x, xT);

    fft_fwd<<<BATCH * HIDDEN, 256, 0, stream>>>(xT, Xc);

    mlp_mfma<<<dim3(65, NB, BATCH), 256, 0, stream>>>(WT1, WT2, bb1, bb2, Xc);

    fft_inv<<<BATCH * HIDDEN, 256, 0, stream>>>(Xc, xT /* as yT */);

    add_out<<<dim3(HIDDEN / 32, S_LEN / 32, BATCH), 256, 0, stream>>>(xT, x, out);
}